// Round 8
// baseline (517.272 us; speedup 1.0000x reference)
//
#include <hip/hip_runtime.h>
#include <hip/hip_bf16.h>
#include <math.h>

// Problem constants (hardcoded from reference)
constexpr int B_ = 4, N_ = 384, H_ = 256, NH_ = 8, DD_ = 32, L_ = 4;
constexpr int M_ = B_ * N_;          // 1536 node rows
constexpr float CUT = 5.0f;
constexpr float PI_ = 3.14159265358979323846f;
constexpr float INVSC = 0.17677669529663687f;  // 1/sqrt(32)
constexpr int TBL_N = 4096;
constexpr int TBL_STRIDE = 4098;

typedef __attribute__((ext_vector_type(8))) short short8;
typedef __attribute__((ext_vector_type(4))) float f32x4;
typedef __attribute__((ext_vector_type(4))) unsigned short u16x4;
using u16 = unsigned short;

__device__ __forceinline__ u16 f2b(float f) {
  __hip_bfloat16 h = __float2bfloat16(f);
  return *reinterpret_cast<u16*>(&h);
}
__device__ __forceinline__ float b2f(u16 u) {
  __hip_bfloat16 h;
  *reinterpret_cast<u16*>(&h) = u;
  return __bfloat162float(h);
}
__device__ __forceinline__ void cvt8(float* o, short8 v) {
#pragma unroll
  for (int i = 0; i < 8; i++) o[i] = b2f((u16)v[i]);
}

__device__ __forceinline__ float wave_sum(float v) {
#pragma unroll
  for (int s = 1; s < 64; s <<= 1) v += __shfl_xor(v, s);
  return v;
}
__device__ __forceinline__ float wave_max(float v) {
#pragma unroll
  for (int s = 1; s < 64; s <<= 1) v = fmaxf(v, __shfl_xor(v, s));
  return v;
}

// ---------------- embed: x = emb[idx] * maskb ----------------
__global__ __launch_bounds__(256) void embed_k(const int* __restrict__ idx,
                                               const float* __restrict__ mask,
                                               const float* __restrict__ emb,
                                               float* __restrict__ X) {
  int e = blockIdx.x * 256 + threadIdx.x;
  int mrow = e >> 8, c = e & 255;
  float mb = mask[mrow] > 0.f ? 1.f : 0.f;
  X[e] = emb[idx[mrow] * H_ + c] * mb;
}

// ---------------- dist: masked distances ----------------
__global__ __launch_bounds__(256) void dist_k(const float* __restrict__ pos,
                                              const float* __restrict__ mask,
                                              float* __restrict__ distm) {
  int e = blockIdx.x * 256 + threadIdx.x;
  int j = e % N_;
  int t = e / N_;
  int i = t % N_;
  int b = t / N_;
  float mi = mask[b * N_ + i], mj = mask[b * N_ + j];
  const float* pi = pos + (size_t)(b * N_ + i) * 3;
  const float* pj = pos + (size_t)(b * N_ + j) * 3;
  float dx = pi[0] - pj[0] + 1e-9f;
  float dy = pi[1] - pj[1] + 1e-9f;
  float dz = pi[2] - pj[2] + 1e-9f;
  float d = sqrtf(dx * dx + dy * dy + dz * dz);
  distm[e] = (mi > 0.f && mj > 0.f) ? d : 1e30f;
}

// ---------------- bias table: block computes 64 t-entries, all heads ---------
__global__ __launch_bounds__(256) void table_k(const float* __restrict__ rb_w1,
                                               const float* __restrict__ rb_b1,
                                               const float* __restrict__ rb_w2,
                                               const float* __restrict__ rb_b2,
                                               float* __restrict__ tbl) {
  constexpr int TT = 64;
  int l = blockIdx.y;
  int t0 = blockIdx.x * TT;
  int tid = threadIdx.x;
  __shared__ float sfA[TT][32];
  __shared__ float hbA[TT][260];
#pragma unroll
  for (int m = 0; m < 8; m++) {
    int idx = m * 256 + tid;
    int tl = idx >> 5, k = idx & 31;
    int t = t0 + tl;
    float d = (t <= TBL_N) ? (t * (CUT / (float)TBL_N)) : 1.7320508075688772e-9f;
    float ang = PI_ * (k + 1) * d * (1.f / CUT);
    sfA[tl][k] = sinf(ang) / (d + 1e-6f);
  }
  __syncthreads();
  float w1c[32];
  const float* w1 = rb_w1 + (size_t)l * DD_ * H_;
#pragma unroll
  for (int k = 0; k < 32; k++) w1c[k] = w1[k * H_ + tid];
  float b1v = rb_b1[l * H_ + tid];
  for (int tl = 0; tl < TT; tl++) {
    float pre = b1v;
    const float4* sfp = (const float4*)sfA[tl];
#pragma unroll
    for (int kq = 0; kq < 8; kq++) {
      float4 s4 = sfp[kq];
      pre += s4.x * w1c[kq * 4] + s4.y * w1c[kq * 4 + 1] + s4.z * w1c[kq * 4 + 2] +
             s4.w * w1c[kq * 4 + 3];
    }
    hbA[tl][tid] = pre / (1.f + __expf(-pre));
  }
  __syncthreads();
  const float* w2 = rb_w2 + (size_t)l * H_ * NH_;
  int o = tid & 7;
  float b2v = rb_b2[l * NH_ + o];
#pragma unroll
  for (int half = 0; half < 2; half++) {
    int tl = (tid >> 3) + half * 32;
    float acc = b2v;
    const float4* hp = (const float4*)hbA[tl];
#pragma unroll 4
    for (int hq = 0; hq < 64; hq++) {
      float4 h4 = hp[hq];
      acc += h4.x * w2[(hq * 4 + 0) * NH_ + o] + h4.y * w2[(hq * 4 + 1) * NH_ + o] +
             h4.z * w2[(hq * 4 + 2) * NH_ + o] + h4.w * w2[(hq * 4 + 3) * NH_ + o];
    }
    int t = t0 + tl;
    if (t < TBL_STRIDE) tbl[(size_t)(l * NH_ + o) * TBL_STRIDE + t] = acc;
  }
}

// ---------------- all-layer bias tensors, one pass over (b,i,j) ----------------
// biasb layout: [l][b][h][i][j] bf16
__global__ __launch_bounds__(256) void bias_all_k(const float* __restrict__ distm,
                                                  const float* __restrict__ tbl,
                                                  u16* __restrict__ biasb) {
  int e = blockIdx.x * 256 + threadIdx.x;  // < B*N*N
  int j = e % N_;
  int t = e / N_;
  int i = t % N_;
  int b = t / N_;
  float d = distm[e];
  size_t plane = (size_t)N_ * N_;
  size_t obase = (size_t)b * NH_ * plane + (size_t)i * N_ + j;
  size_t lstride = (size_t)B_ * NH_ * plane;
  if (d <= CUT) {
    float u = d * ((float)TBL_N / CUT);
    int ix = (int)u;
    ix = ix > TBL_N - 1 ? TBL_N - 1 : ix;
    float fr = u - (float)ix;
    bool diag = (i == j);
#pragma unroll
    for (int l = 0; l < L_; l++)
#pragma unroll
      for (int h = 0; h < NH_; h++) {
        const float* tblh = tbl + (size_t)(l * NH_ + h) * TBL_STRIDE;
        float v = diag ? tblh[TBL_N + 1] : (tblh[ix] * (1.f - fr) + tblh[ix + 1] * fr);
        biasb[(size_t)l * lstride + obase + (size_t)h * plane] = f2b(v);
      }
  } else {
#pragma unroll
    for (int l = 0; l < L_; l++)
#pragma unroll
      for (int h = 0; h < NH_; h++)
        biasb[(size_t)l * lstride + obase + (size_t)h * plane] = 0xFF80;  // -inf
  }
}

// ---------------- combined weight transpose: W[K][N] fp32 -> WT[N][K] bf16 --------
struct TrJob {
  const float* src;
  u16* dst;
  int K, N, nx, ny, nz, base, dstride;
};
struct TrJobs {
  TrJob j[7];
};
__global__ __launch_bounds__(256) void tr_all_k(TrJobs jobs) {
  __shared__ float t[32][33];
  int bid = blockIdx.x;
  int ji = 0;
#pragma unroll
  for (int q = 1; q < 7; q++)
    if (bid >= jobs.j[q].base) ji = q;
  const TrJob& J = jobs.j[ji];
  int local = bid - J.base;
  int z = local / (J.nx * J.ny);
  int r2 = local % (J.nx * J.ny);
  int ky = r2 / J.nx, kx = r2 % J.nx;
  int n0 = kx * 32, k0 = ky * 32;
  const float* s = J.src + (size_t)z * J.K * J.N;
  u16* d = J.dst + (size_t)z * J.dstride;
  int tid = threadIdx.x;
  int r = tid >> 3, c4 = (tid & 7) * 4;
  float4 v = *(const float4*)(s + (size_t)(k0 + r) * J.N + n0 + c4);
  t[r][c4 + 0] = v.x;
  t[r][c4 + 1] = v.y;
  t[r][c4 + 2] = v.z;
  t[r][c4 + 3] = v.w;
  __syncthreads();
  u16x4 o;
  o[0] = f2b(t[c4 + 0][r]);
  o[1] = f2b(t[c4 + 1][r]);
  o[2] = f2b(t[c4 + 2][r]);
  o[3] = f2b(t[c4 + 3][r]);
  *(u16x4*)(d + (size_t)(n0 + r) * J.K + k0 + c4) = o;
}

// ---------------- bf16 MFMA GEMM (generic, chunked K) ----------------
// C[M,Nc] = act(A'[M,K] @ W[K,Nc] + bias) (+resid); A' = PRE ? A*sigmoid(G) : A
template <int ACT, bool RES, bool PRE, bool OBF>
__global__ __launch_bounds__(256) void mgemm_k(const void* __restrict__ Av,
                                               const u16* __restrict__ WT,
                                               const float* __restrict__ bias,
                                               const float* __restrict__ resid,
                                               void* __restrict__ Cv, int K, int Nc,
                                               int lda, const float* __restrict__ G,
                                               const float* __restrict__ bias2) {
  __shared__ u16 As[64 * 128];
  __shared__ u16 Bs[64 * 128];
  const int m0 = blockIdx.y * 64, n0 = blockIdx.x * 64;
  const int tid = threadIdx.x;
  const int wave = tid >> 6, lane = tid & 63;
  const int wr = wave >> 1, wc = wave & 1, lr = lane & 15, lg = lane >> 4;
  f32x4 acc[2][2] = {};
  const int srow = tid >> 2, sp = tid & 3;
  for (int k0 = 0; k0 < K; k0 += 128) {
#pragma unroll
    for (int s4 = 0; s4 < 4; s4++) {
      int s = sp * 4 + s4;
      int phys = s ^ (srow & 15);
      if (PRE) {
        const float* ap = (const float*)Av + (size_t)(m0 + srow) * lda + k0 + s * 8;
        const float* gp = G + (size_t)(m0 + srow) * lda + k0 + s * 8;
        float4 a0 = *(const float4*)ap;
        float4 a1 = *(const float4*)(ap + 4);
        float4 g0 = *(const float4*)gp;
        float4 g1 = *(const float4*)(gp + 4);
        short8 vv;
        vv[0] = (short)f2b(a0.x / (1.f + __expf(-g0.x)));
        vv[1] = (short)f2b(a0.y / (1.f + __expf(-g0.y)));
        vv[2] = (short)f2b(a0.z / (1.f + __expf(-g0.z)));
        vv[3] = (short)f2b(a0.w / (1.f + __expf(-g0.w)));
        vv[4] = (short)f2b(a1.x / (1.f + __expf(-g1.x)));
        vv[5] = (short)f2b(a1.y / (1.f + __expf(-g1.y)));
        vv[6] = (short)f2b(a1.z / (1.f + __expf(-g1.z)));
        vv[7] = (short)f2b(a1.w / (1.f + __expf(-g1.w)));
        *(short8*)&As[srow * 128 + phys * 8] = vv;
      } else {
        const u16* Ab = (const u16*)Av;
        short8 v = *(const short8*)(Ab + (size_t)(m0 + srow) * lda + k0 + s * 8);
        *(short8*)&As[srow * 128 + phys * 8] = v;
      }
      short8 w = *(const short8*)(WT + (size_t)(n0 + srow) * K + k0 + s * 8);
      *(short8*)&Bs[srow * 128 + phys * 8] = w;
    }
    __syncthreads();
#pragma unroll
    for (int kk = 0; kk < 4; kk++) {
      int slot = kk * 4 + lg;
      short8 af[2], bf_[2];
#pragma unroll
      for (int i = 0; i < 2; i++) {
        int row = wr * 32 + i * 16 + lr;
        af[i] = *(const short8*)&As[row * 128 + (slot ^ (row & 15)) * 8];
      }
#pragma unroll
      for (int j = 0; j < 2; j++) {
        int row = wc * 32 + j * 16 + lr;
        bf_[j] = *(const short8*)&Bs[row * 128 + (slot ^ (row & 15)) * 8];
      }
#pragma unroll
      for (int i = 0; i < 2; i++)
#pragma unroll
        for (int j = 0; j < 2; j++)
          acc[i][j] = __builtin_amdgcn_mfma_f32_16x16x32_bf16(af[i], bf_[j], acc[i][j], 0, 0, 0);
    }
    __syncthreads();
  }
#pragma unroll
  for (int i = 0; i < 2; i++)
#pragma unroll
    for (int j = 0; j < 2; j++)
#pragma unroll
      for (int rg = 0; rg < 4; rg++) {
        int row = m0 + wr * 32 + i * 16 + lg * 4 + rg;
        int col = n0 + wc * 32 + j * 16 + lr;
        float v = acc[i][j][rg] + bias[col];
        if (ACT == 1) v = v / (1.f + __expf(-v));
        if (ACT == 2) v = 0.5f * v * (1.f + erff(v * 0.70710678118654752f));
        if (RES) v += resid[(size_t)row * Nc + col];
        if (OBF)
          ((u16*)Cv)[(size_t)row * Nc + col] = f2b(v);
        else
          ((float*)Cv)[(size_t)row * Nc + col] = v;
      }
}

// ---------------- LN-fused bf16 MFMA GEMM (K=256 fixed) ----------------
// C[M,Nc] = act(bf16(LN(X)) @ W + bias); LN computed in A-staging.
// ACT: 1 silu, 2 gelu, 3 = plain bias for col<768 / silu+bias2 for col>=768.
template <int ACT, bool OBF>
__global__ __launch_bounds__(256) void lngemm_k(const float* __restrict__ X,
                                                const float* __restrict__ lng,
                                                const float* __restrict__ lnb,
                                                const u16* __restrict__ WT,
                                                const float* __restrict__ bias,
                                                void* __restrict__ Cv, int Nc,
                                                const float* __restrict__ bias2) {
  __shared__ u16 As[64 * 256];
  __shared__ u16 Bs[64 * 256];
  const int m0 = blockIdx.y * 64, n0 = blockIdx.x * 64;
  const int tid = threadIdx.x;
  const int wave = tid >> 6, lane = tid & 63;
  const int wr = wave >> 1, wc = wave & 1, lr = lane & 15, lg = lane >> 4;
  // ---- A staging with fused LN: row = tid>>2, quarter q = tid&3 (64 elems each)
  {
    const int row = tid >> 2, q = tid & 3;
    const float* xr = X + (size_t)(m0 + row) * 256 + q * 64;
    float s = 0.f, sq = 0.f;
#pragma unroll
    for (int i4 = 0; i4 < 16; i4++) {
      float4 v = *(const float4*)(xr + i4 * 4);
      s += v.x + v.y + v.z + v.w;
      sq += v.x * v.x + v.y * v.y + v.z * v.z + v.w * v.w;
    }
    s += __shfl_xor(s, 1);
    s += __shfl_xor(s, 2);
    sq += __shfl_xor(sq, 1);
    sq += __shfl_xor(sq, 2);
    float m = s * (1.f / 256.f);
    float var = sq * (1.f / 256.f) - m * m;
    float rs = rsqrtf(var + 1e-5f);
#pragma unroll
    for (int i8 = 0; i8 < 8; i8++) {
      int c0 = q * 64 + i8 * 8;
      float4 v0 = *(const float4*)(xr + i8 * 8);
      float4 v1 = *(const float4*)(xr + i8 * 8 + 4);
      float4 g0 = *(const float4*)(lng + c0);
      float4 g1 = *(const float4*)(lng + c0 + 4);
      float4 b0 = *(const float4*)(lnb + c0);
      float4 b1 = *(const float4*)(lnb + c0 + 4);
      short8 vv;
      vv[0] = (short)f2b((v0.x - m) * rs * g0.x + b0.x);
      vv[1] = (short)f2b((v0.y - m) * rs * g0.y + b0.y);
      vv[2] = (short)f2b((v0.z - m) * rs * g0.z + b0.z);
      vv[3] = (short)f2b((v0.w - m) * rs * g0.w + b0.w);
      vv[4] = (short)f2b((v1.x - m) * rs * g1.x + b1.x);
      vv[5] = (short)f2b((v1.y - m) * rs * g1.y + b1.y);
      vv[6] = (short)f2b((v1.z - m) * rs * g1.z + b1.z);
      vv[7] = (short)f2b((v1.w - m) * rs * g1.w + b1.w);
      int chunk = q * 8 + i8;
      *(short8*)&As[row * 256 + (chunk ^ (row & 15)) * 8] = vv;
    }
    // ---- B staging (full 64x256)
    const u16* wr_ = WT + (size_t)(n0 + row) * 256;
#pragma unroll
    for (int s4 = 0; s4 < 8; s4++) {
      int chunk = q * 8 + s4;
      short8 w = *(const short8*)(wr_ + chunk * 8);
      *(short8*)&Bs[row * 256 + (chunk ^ (row & 15)) * 8] = w;
    }
  }
  __syncthreads();
  f32x4 acc[2][2] = {};
#pragma unroll
  for (int half = 0; half < 2; half++)
#pragma unroll
    for (int kk = 0; kk < 4; kk++) {
      int chunk = half * 16 + kk * 4 + lg;
      short8 af[2], bf_[2];
#pragma unroll
      for (int i = 0; i < 2; i++) {
        int row = wr * 32 + i * 16 + lr;
        af[i] = *(const short8*)&As[row * 256 + (chunk ^ (row & 15)) * 8];
      }
#pragma unroll
      for (int j = 0; j < 2; j++) {
        int row = wc * 32 + j * 16 + lr;
        bf_[j] = *(const short8*)&Bs[row * 256 + (chunk ^ (row & 15)) * 8];
      }
#pragma unroll
      for (int i = 0; i < 2; i++)
#pragma unroll
        for (int j = 0; j < 2; j++)
          acc[i][j] = __builtin_amdgcn_mfma_f32_16x16x32_bf16(af[i], bf_[j], acc[i][j], 0, 0, 0);
    }
#pragma unroll
  for (int i = 0; i < 2; i++)
#pragma unroll
    for (int j = 0; j < 2; j++)
#pragma unroll
      for (int rg = 0; rg < 4; rg++) {
        int row = m0 + wr * 32 + i * 16 + lg * 4 + rg;
        int col = n0 + wc * 32 + j * 16 + lr;
        float v;
        if (ACT == 3) {
          float bv = (col < 768) ? bias[col] : bias2[col - 768];
          v = acc[i][j][rg] + bv;
          if (col >= 768) v = v / (1.f + __expf(-v));
        } else {
          v = acc[i][j][rg] + bias[col];
          if (ACT == 1) v = v / (1.f + __expf(-v));
          if (ACT == 2) v = 0.5f * v * (1.f + erff(v * 0.70710678118654752f));
        }
        if (OBF)
          ((u16*)Cv)[(size_t)row * Nc + col] = f2b(v);
        else
          ((float*)Cv)[(size_t)row * Nc + col] = v;
      }
}

// ---------------- fused attention: full-row softmax, precomputed bias ----------
// grid = B*NH*(N/8); 256 threads = 4 waves; wave handles 2 query rows.
// red[] aliases Ks LDS (dead by epilogue; guarded by __syncthreads).
__global__ __launch_bounds__(256) void attn_k(const u16* __restrict__ qkv,
                                              const u16* __restrict__ biasb,
                                              float* __restrict__ ctx, int qs) {
  int bid = blockIdx.x;
  int it = bid % (N_ / 8);
  int t2 = bid / (N_ / 8);
  int hh = t2 % NH_;
  int b = t2 / NH_;
  int i0 = it * 8;
  __shared__ __align__(16) u16 Ks[384 * 32];
  __shared__ __align__(16) u16 Vs[384 * 32];
  __shared__ float Qs[8][32];
  float (*red)[32][36] = (float(*)[32][36])Ks;
  int tid = threadIdx.x;
  const size_t bb = (size_t)b * N_;
  if (tid < 64) {
    int r = tid >> 3, c4 = (tid & 7) * 4;
    u16x4 q4 = *(const u16x4*)(qkv + (bb + i0 + r) * qs + hh * 32 + c4);
    Qs[r][c4 + 0] = b2f(q4[0]);
    Qs[r][c4 + 1] = b2f(q4[1]);
    Qs[r][c4 + 2] = b2f(q4[2]);
    Qs[r][c4 + 3] = b2f(q4[3]);
  }
#pragma unroll
  for (int m = 0; m < 6; m++) {
    int idx = m * 256 + tid;  // < 1536
    int row = idx >> 2, c = idx & 3;
    int phys = c ^ ((row >> 1) & 3);
    const u16* kb = qkv + (bb + row) * qs + 256 + hh * 32 + c * 8;
    *(short8*)&Ks[row * 32 + phys * 8] = *(const short8*)kb;
    *(short8*)&Vs[row * 32 + phys * 8] = *(const short8*)(kb + 256);
  }
  __syncthreads();
  int wave = tid >> 6, lane = tid & 63;
  int ra = wave * 2;
  const u16* bptr = biasb + (size_t)(b * NH_ + hh) * N_ * N_;
  const int sw = (lane >> 1) & 3;
  float lg[2][6];
  for (int t = 0; t < 6; t++) {
    int j = t * 64 + lane;
    float Kr[32];
#pragma unroll
    for (int c = 0; c < 4; c++) cvt8(&Kr[c * 8], *(const short8*)&Ks[j * 32 + (c ^ sw) * 8]);
#pragma unroll
    for (int r = 0; r < 2; r++) {
      int irow = i0 + ra + r;
      float acc = 0.f;
      const float4* qp = (const float4*)Qs[ra + r];
#pragma unroll
      for (int q = 0; q < 8; q++) {
        float4 qq = qp[q];
        acc += qq.x * Kr[q * 4] + qq.y * Kr[q * 4 + 1] + qq.z * Kr[q * 4 + 2] + qq.w * Kr[q * 4 + 3];
      }
      float bv = b2f(bptr[(size_t)irow * N_ + j]);
      lg[r][t] = acc * INVSC + bv;
    }
  }
  float Ls[2];
#pragma unroll
  for (int r = 0; r < 2; r++) {
    float mx = lg[r][0];
#pragma unroll
    for (int t = 1; t < 6; t++) mx = fmaxf(mx, lg[r][t]);
    mx = wave_max(mx);
    float s = 0.f;
#pragma unroll
    for (int t = 0; t < 6; t++) {
      lg[r][t] = __expf(lg[r][t] - mx);
      s += lg[r][t];
    }
    Ls[r] = wave_sum(s);
  }
  float pc[2][32];
#pragma unroll
  for (int r = 0; r < 2; r++)
#pragma unroll
    for (int k = 0; k < 32; k++) pc[r][k] = 0.f;
  for (int t = 0; t < 6; t++) {
    int j = t * 64 + lane;
    float Vr[32];
#pragma unroll
    for (int c = 0; c < 4; c++) cvt8(&Vr[c * 8], *(const short8*)&Vs[j * 32 + (c ^ sw) * 8]);
#pragma unroll
    for (int r = 0; r < 2; r++)
#pragma unroll
      for (int k = 0; k < 32; k++) pc[r][k] += lg[r][t] * Vr[k];
  }
  int kout = lane >> 1, hf = lane & 1;
#pragma unroll
  for (int r = 0; r < 2; r++) {
    __syncthreads();  // also protects Ks (aliased by red) from in-flight K/V reads
#pragma unroll
    for (int k = 0; k < 32; k++) {
      float v = pc[r][k] + __shfl_xor(pc[r][k], 32);
      if (lane < 32) red[wave][k][lane] = v;
    }
    __syncthreads();
    float s = 0.f;
#pragma unroll
    for (int u = 0; u < 4; u++) {
      float4 q4 = *(const float4*)&red[wave][kout][hf * 16 + u * 4];
      s += q4.x + q4.y + q4.z + q4.w;
    }
    s += __shfl_xor(s, 1);
    if (hf == 0) {
      int row = i0 + ra + r;
      ctx[(bb + row) * H_ + hh * 32 + kout] = s / Ls[r];
    }
  }
}

// ---------------- energy: masked mean over nodes then dot with eh_w ----------------
__global__ __launch_bounds__(256) void energy_k(const float* __restrict__ p2,
                                                const float* __restrict__ mask,
                                                const float* __restrict__ ehw,
                                                const float* __restrict__ ehb,
                                                float* __restrict__ out) {
  int b = blockIdx.x, h = threadIdx.x;
  float s = 0.f, cnt = 0.f;
#pragma unroll 4
  for (int i = 0; i < N_; i++) {
    float m = mask[b * N_ + i] > 0.f ? 1.f : 0.f;
    s += p2[(size_t)(b * N_ + i) * H_ + h] * m;
    cnt += m;
  }
  float val = s * ehw[h];
  __shared__ float red[256];
  red[h] = val;
  __syncthreads();
  for (int st = 128; st > 0; st >>= 1) {
    if (h < st) red[h] += red[h + st];
    __syncthreads();
  }
  if (h == 0) {
    float c = cnt < 1.f ? 1.f : cnt;
    out[b] = red[0] / c + ehb[0];
  }
}

extern "C" void kernel_launch(void* const* d_in, const int* in_sizes, int n_in,
                              void* d_out, int out_size, void* d_ws, size_t ws_size,
                              hipStream_t stream) {
  const int* node_idx = (const int*)d_in[0];
  const float* positions = (const float*)d_in[1];
  const float* mask = (const float*)d_in[2];
  const float* emb = (const float*)d_in[3];
  const float* ln1_g = (const float*)d_in[4];
  const float* ln1_b = (const float*)d_in[5];
  const float* qkv_w = (const float*)d_in[6];
  const float* qkv_b = (const float*)d_in[7];
  const float* out_w = (const float*)d_in[8];
  const float* out_b = (const float*)d_in[9];
  const float* rb_w1 = (const float*)d_in[10];
  const float* rb_b1 = (const float*)d_in[11];
  const float* rb_w2 = (const float*)d_in[12];
  const float* rb_b2 = (const float*)d_in[13];
  const float* gate_w1 = (const float*)d_in[14];
  const float* gate_b1 = (const float*)d_in[15];
  const float* gate_w2 = (const float*)d_in[16];
  const float* gate_b2 = (const float*)d_in[17];
  const float* ln2_g = (const float*)d_in[18];
  const float* ln2_b = (const float*)d_in[19];
  const float* ff_w1 = (const float*)d_in[20];
  const float* ff_b1 = (const float*)d_in[21];
  const float* ff_w2 = (const float*)d_in[22];
  const float* ff_b2 = (const float*)d_in[23];
  const float* pool_g = (const float*)d_in[24];
  const float* pool_beta = (const float*)d_in[25];
  const float* pool_w = (const float*)d_in[26];
  const float* pool_b = (const float*)d_in[27];
  const float* eh_w = (const float*)d_in[28];
  const float* eh_b = (const float*)d_in[29];
  float* eout = (float*)d_out;

  // workspace layout (bytes)
  char* W8 = (char*)d_ws;
  float* x = (float*)(W8 + 0);              // 1572864 B (M x 256 f32)
  u16* qgb = (u16*)(W8 + 1572864);          // 3145728 B (M x 1024 bf16: q|k|v|g1)
  float* ctx = (float*)(W8 + 4718592);      // 1572864 B
  float* g2 = (float*)(W8 + 6291456);       // 1572864 B
  u16* ffb = (u16*)(W8 + 8650752);          // 1572864 B (M x 512 bf16)
  float* distm = (float*)(W8 + 10223616);   // 2359296 B
  float* tbl = (float*)(W8 + 12582912);     // 524544 B
  u16* wt = (u16*)(W8 + 13107456);          // 5373952 B
  u16* wt_qg = wt;                  // 4 x 1024 x 256
  u16* wt_out = wt + 1048576;       // 4 x 256 x 256
  u16* wt_g2 = wt + 1310720;
  u16* wt_f1 = wt + 1572864;        // 4 x 512 x 256
  u16* wt_f2 = wt + 2097152;        // 4 x 256 x 512
  u16* wt_p = wt + 2621440;         // 256 x 256
  u16* biasb = (u16*)(W8 + 18481408);       // 4 x 9437184 B ([l][b][h][i][j] bf16)
  const size_t bias_lstride = (size_t)B_ * NH_ * N_ * N_;

  // ---- setup ----
  embed_k<<<M_ * H_ / 256, 256, 0, stream>>>(node_idx, mask, emb, x);
  dist_k<<<B_ * N_ * N_ / 256, 256, 0, stream>>>(positions, mask, distm);
  table_k<<<dim3(65, L_), 256, 0, stream>>>(rb_w1, rb_b1, rb_w2, rb_b2, tbl);
  {
    TrJobs jobs;
    // qkv: K=256,N=768,nx=24,ny=8,nz=4 -> 768 blocks, dst wt_qg stride 262144
    jobs.j[0] = {qkv_w, wt_qg, 256, 768, 24, 8, 4, 0, 262144};
    jobs.j[1] = {gate_w1, wt_qg + 768 * 256, 256, 256, 8, 8, 4, 768, 262144};
    jobs.j[2] = {out_w, wt_out, 256, 256, 8, 8, 4, 1024, 65536};
    jobs.j[3] = {gate_w2, wt_g2, 256, 256, 8, 8, 4, 1280, 65536};
    jobs.j[4] = {ff_w1, wt_f1, 256, 512, 16, 8, 4, 1536, 131072};
    jobs.j[5] = {ff_w2, wt_f2, 512, 256, 8, 16, 4, 2048, 131072};
    jobs.j[6] = {pool_w, wt_p, 256, 256, 8, 8, 1, 2560, 65536};
    tr_all_k<<<2624, 256, 0, stream>>>(jobs);
  }
  bias_all_k<<<B_ * N_ * N_ / 256, 256, 0, stream>>>(distm, tbl, biasb);

  for (int l = 0; l < L_; l++) {
    const float* qb = qkv_b + (size_t)l * 3 * H_;
    const float* ob = out_b + (size_t)l * H_;
    const float* gb1 = gate_b1 + (size_t)l * H_;
    const float* gb2 = gate_b2 + (size_t)l * H_;
    const float* fb1 = ff_b1 + (size_t)l * 2 * H_;
    const float* fb2 = ff_b2 + (size_t)l * H_;
    u16* wqg = wt_qg + (size_t)l * 1024 * 256;
    u16* wo = wt_out + (size_t)l * 256 * 256;
    u16* wg2 = wt_g2 + (size_t)l * 256 * 256;
    u16* wf1 = wt_f1 + (size_t)l * 512 * 256;
    u16* wf2 = wt_f2 + (size_t)l * 256 * 512;

    // qgb = bf16(LN1(x)) @ [qkv_w | gate_w1] (+biases, silu on g1 cols)
    lngemm_k<3, true><<<dim3(16, 24), 256, 0, stream>>>(
        x, ln1_g + l * H_, ln1_b + l * H_, wqg, qb, qgb, 1024, gb1);
    // ctx = attention(qgb, biasb[l])
    attn_k<<<B_ * NH_ * (N_ / 8), 256, 0, stream>>>(
        qgb, biasb + (size_t)l * bias_lstride, ctx, 1024);
    // g2 = g1 @ gate_w2 + gate_b2 (fp32 out); g1 = qgb cols 768..1023
    mgemm_k<0, false, false, false><<<dim3(4, 24), 256, 0, stream>>>(
        (const void*)(qgb + 768), wg2, gb2, nullptr, g2, 256, 256, 1024, nullptr, nullptr);
    // x = x + bf16(ctx * sigmoid(g2)) @ out_w + out_b
    mgemm_k<0, true, true, false><<<dim3(4, 24), 256, 0, stream>>>(
        ctx, wo, ob, x, x, 256, 256, 256, g2, nullptr);
    // ffb = bf16(gelu(bf16(LN2(x)) @ ff_w1 + ff_b1))
    lngemm_k<2, true><<<dim3(8, 24), 256, 0, stream>>>(
        x, ln2_g + l * H_, ln2_b + l * H_, wf1, fb1, ffb, 512, nullptr);
    // x = x + ffb @ ff_w2 + ff_b2
    mgemm_k<0, true, false, false><<<dim3(4, 24), 256, 0, stream>>>(
        ffb, wf2, fb2, x, x, 512, 256, 512, nullptr, nullptr);
  }

  // pooling head: ctx = silu(bf16(LN(x)) @ pool_w + pool_b)
  lngemm_k<1, false><<<dim3(4, 24), 256, 0, stream>>>(
      x, pool_g, pool_beta, wt_p, pool_b, ctx, 256, nullptr);
  energy_k<<<B_, 256, 0, stream>>>(ctx, mask, eh_w, eh_b, eout);
}

// Round 9
// 387.745 us; speedup vs baseline: 1.3341x; 1.3341x over previous
//
#include <hip/hip_runtime.h>
#include <hip/hip_bf16.h>
#include <math.h>

// Problem constants (hardcoded from reference)
constexpr int B_ = 4, N_ = 384, H_ = 256, NH_ = 8, DD_ = 32, L_ = 4;
constexpr int M_ = B_ * N_;          // 1536 node rows
constexpr float CUT = 5.0f;
constexpr float PI_ = 3.14159265358979323846f;
constexpr float INVSC = 0.17677669529663687f;  // 1/sqrt(32)
constexpr int TBL_N = 4096;
constexpr int TBL_STRIDE = 4098;

typedef __attribute__((ext_vector_type(8))) short short8;
typedef __attribute__((ext_vector_type(4))) float f32x4;
typedef __attribute__((ext_vector_type(4))) unsigned short u16x4;
using u16 = unsigned short;

__device__ __forceinline__ u16 f2b(float f) {
  __hip_bfloat16 h = __float2bfloat16(f);
  return *reinterpret_cast<u16*>(&h);
}
__device__ __forceinline__ float b2f(u16 u) {
  __hip_bfloat16 h;
  *reinterpret_cast<u16*>(&h) = u;
  return __bfloat162float(h);
}
__device__ __forceinline__ void cvt8(float* o, short8 v) {
#pragma unroll
  for (int i = 0; i < 8; i++) o[i] = b2f((u16)v[i]);
}

__device__ __forceinline__ float wave_sum(float v) {
#pragma unroll
  for (int s = 1; s < 64; s <<= 1) v += __shfl_xor(v, s);
  return v;
}
__device__ __forceinline__ float wave_max(float v) {
#pragma unroll
  for (int s = 1; s < 64; s <<= 1) v = fmaxf(v, __shfl_xor(v, s));
  return v;
}

// ---------------- embed: x = emb[idx] * maskb ----------------
__global__ __launch_bounds__(256) void embed_k(const int* __restrict__ idx,
                                               const float* __restrict__ mask,
                                               const float* __restrict__ emb,
                                               float* __restrict__ X) {
  int e = blockIdx.x * 256 + threadIdx.x;
  int mrow = e >> 8, c = e & 255;
  float mb = mask[mrow] > 0.f ? 1.f : 0.f;
  X[e] = emb[idx[mrow] * H_ + c] * mb;
}

// ---------------- dist: masked distances ----------------
__global__ __launch_bounds__(256) void dist_k(const float* __restrict__ pos,
                                              const float* __restrict__ mask,
                                              float* __restrict__ distm) {
  int e = blockIdx.x * 256 + threadIdx.x;
  int j = e % N_;
  int t = e / N_;
  int i = t % N_;
  int b = t / N_;
  float mi = mask[b * N_ + i], mj = mask[b * N_ + j];
  const float* pi = pos + (size_t)(b * N_ + i) * 3;
  const float* pj = pos + (size_t)(b * N_ + j) * 3;
  float dx = pi[0] - pj[0] + 1e-9f;
  float dy = pi[1] - pj[1] + 1e-9f;
  float dz = pi[2] - pj[2] + 1e-9f;
  float d = sqrtf(dx * dx + dy * dy + dz * dz);
  distm[e] = (mi > 0.f && mj > 0.f) ? d : 1e30f;
}

// ---------------- bias table (t-major output): tbl2[t][l*8+h] ----------------
// grid dim3(65, L_), 256 threads.
__global__ __launch_bounds__(256) void table_k(const float* __restrict__ rb_w1,
                                               const float* __restrict__ rb_b1,
                                               const float* __restrict__ rb_w2,
                                               const float* __restrict__ rb_b2,
                                               float* __restrict__ tbl2) {
  constexpr int TT = 64;
  int l = blockIdx.y;
  int t0 = blockIdx.x * TT;
  int tid = threadIdx.x;
  __shared__ float sfA[TT][32];
  __shared__ float hbA[TT][260];
#pragma unroll
  for (int m = 0; m < 8; m++) {
    int idx = m * 256 + tid;
    int tl = idx >> 5, k = idx & 31;
    int t = t0 + tl;
    float d = (t <= TBL_N) ? (t * (CUT / (float)TBL_N)) : 1.7320508075688772e-9f;
    float ang = PI_ * (k + 1) * d * (1.f / CUT);
    sfA[tl][k] = sinf(ang) / (d + 1e-6f);
  }
  __syncthreads();
  float w1c[32];
  const float* w1 = rb_w1 + (size_t)l * DD_ * H_;
#pragma unroll
  for (int k = 0; k < 32; k++) w1c[k] = w1[k * H_ + tid];
  float b1v = rb_b1[l * H_ + tid];
  for (int tl = 0; tl < TT; tl++) {
    float pre = b1v;
    const float4* sfp = (const float4*)sfA[tl];
#pragma unroll
    for (int kq = 0; kq < 8; kq++) {
      float4 s4 = sfp[kq];
      pre += s4.x * w1c[kq * 4] + s4.y * w1c[kq * 4 + 1] + s4.z * w1c[kq * 4 + 2] +
             s4.w * w1c[kq * 4 + 3];
    }
    hbA[tl][tid] = pre / (1.f + __expf(-pre));
  }
  __syncthreads();
  const float* w2 = rb_w2 + (size_t)l * H_ * NH_;
  int o = tid & 7;
  float b2v = rb_b2[l * NH_ + o];
#pragma unroll
  for (int half = 0; half < 2; half++) {
    int tl = (tid >> 3) + half * 32;
    float acc = b2v;
    const float4* hp = (const float4*)hbA[tl];
#pragma unroll 4
    for (int hq = 0; hq < 64; hq++) {
      float4 h4 = hp[hq];
      acc += h4.x * w2[(hq * 4 + 0) * NH_ + o] + h4.y * w2[(hq * 4 + 1) * NH_ + o] +
             h4.z * w2[(hq * 4 + 2) * NH_ + o] + h4.w * w2[(hq * 4 + 3) * NH_ + o];
    }
    int t = t0 + tl;
    // rows 0..4097 are real; row 4098 (read as lerp partner of diag row, fr=0)
    // gets the diag value too -> finite, never used.
    if (t <= TBL_STRIDE) tbl2[(size_t)t * 32 + l * NH_ + o] = acc;
  }
}

// ---------------- all-layer bias tensors, vectorized row-lerp ----------------
// biasb layout: [l][b][h][i][j] bf16. One thread per edge; rows ix/ix+1 of
// tbl2 are 2x 128B contiguous loads (16 independent float4s) -> ILP, no
// serial scalar gather chain (round-8 bias_all_k was VGPR=8, gather-serial).
__global__ __launch_bounds__(256) void bias_all2_k(const float* __restrict__ distm,
                                                   const float* __restrict__ tbl2,
                                                   u16* __restrict__ biasb) {
  int e = blockIdx.x * 256 + threadIdx.x;  // < B*N*N
  int j = e % N_;
  int t = e / N_;
  int i = t % N_;
  int b = t / N_;
  float d = distm[e];
  size_t plane = (size_t)N_ * N_;
  size_t obase = (size_t)b * NH_ * plane + (size_t)i * N_ + j;
  size_t lstride = (size_t)B_ * NH_ * plane;
  if (d <= CUT) {
    int ixrow;
    float fr;
    if (i == j) {
      ixrow = TBL_N + 1;  // diag row
      fr = 0.f;
    } else {
      float u = d * ((float)TBL_N / CUT);
      int ix = (int)u;
      ix = ix > TBL_N - 1 ? TBL_N - 1 : ix;
      fr = u - (float)ix;
      ixrow = ix;
    }
    const float4* r0 = (const float4*)(tbl2 + (size_t)ixrow * 32);
    const float4* r1 = (const float4*)(tbl2 + (size_t)(ixrow + 1) * 32);
    float4 a0[8], a1[8];
#pragma unroll
    for (int q = 0; q < 8; q++) {
      a0[q] = r0[q];
      a1[q] = r1[q];
    }
    float w0 = 1.f - fr;
#pragma unroll
    for (int q = 0; q < 8; q++) {
      float v0[4] = {a0[q].x, a0[q].y, a0[q].z, a0[q].w};
      float v1[4] = {a1[q].x, a1[q].y, a1[q].z, a1[q].w};
#pragma unroll
      for (int c = 0; c < 4; c++) {
        int lh = q * 4 + c;
        int l = lh >> 3, h = lh & 7;
        float v = v0[c] * w0 + v1[c] * fr;
        biasb[(size_t)l * lstride + obase + (size_t)h * plane] = f2b(v);
      }
    }
  } else {
#pragma unroll
    for (int lh = 0; lh < 32; lh++) {
      int l = lh >> 3, h = lh & 7;
      biasb[(size_t)l * lstride + obase + (size_t)h * plane] = 0xFF80;  // -inf
    }
  }
}

// ---------------- LayerNorm (row of 256) -> bf16 output ----------------
__global__ __launch_bounds__(256) void ln_k(const float* __restrict__ X,
                                            const float* __restrict__ g,
                                            const float* __restrict__ bta,
                                            u16* __restrict__ O) {
  int wave = threadIdx.x >> 6, lane = threadIdx.x & 63;
  int row = blockIdx.x * 4 + wave;
  const float* xr = X + (size_t)row * H_;
  float4 v = *(const float4*)(xr + lane * 4);
  float s = v.x + v.y + v.z + v.w;
  s = wave_sum(s);
  float m = s * (1.f / H_);
  float dx = v.x - m, dy = v.y - m, dz = v.z - m, dw = v.w - m;
  float vs = dx * dx + dy * dy + dz * dz + dw * dw;
  vs = wave_sum(vs);
  float rs = rsqrtf(vs * (1.f / H_) + 1e-5f);
  float4 gg = *(const float4*)(g + lane * 4);
  float4 bb = *(const float4*)(bta + lane * 4);
  u16x4 o;
  o[0] = f2b(dx * rs * gg.x + bb.x);
  o[1] = f2b(dy * rs * gg.y + bb.y);
  o[2] = f2b(dz * rs * gg.z + bb.z);
  o[3] = f2b(dw * rs * gg.w + bb.w);
  *(u16x4*)(O + (size_t)row * H_ + lane * 4) = o;
}

// ---------------- combined weight transpose: W[K][N] fp32 -> WT[N][K] bf16 --------
struct TrJob {
  const float* src;
  u16* dst;
  int K, N, nx, ny, nz, base, dstride;
};
struct TrJobs {
  TrJob j[7];
};
__global__ __launch_bounds__(256) void tr_all_k(TrJobs jobs) {
  __shared__ float t[32][33];
  int bid = blockIdx.x;
  int ji = 0;
#pragma unroll
  for (int q = 1; q < 7; q++)
    if (bid >= jobs.j[q].base) ji = q;
  const TrJob& J = jobs.j[ji];
  int local = bid - J.base;
  int z = local / (J.nx * J.ny);
  int r2 = local % (J.nx * J.ny);
  int ky = r2 / J.nx, kx = r2 % J.nx;
  int n0 = kx * 32, k0 = ky * 32;
  const float* s = J.src + (size_t)z * J.K * J.N;
  u16* d = J.dst + (size_t)z * J.dstride;
  int tid = threadIdx.x;
  int r = tid >> 3, c4 = (tid & 7) * 4;
  float4 v = *(const float4*)(s + (size_t)(k0 + r) * J.N + n0 + c4);
  t[r][c4 + 0] = v.x;
  t[r][c4 + 1] = v.y;
  t[r][c4 + 2] = v.z;
  t[r][c4 + 3] = v.w;
  __syncthreads();
  u16x4 o;
  o[0] = f2b(t[c4 + 0][r]);
  o[1] = f2b(t[c4 + 1][r]);
  o[2] = f2b(t[c4 + 2][r]);
  o[3] = f2b(t[c4 + 3][r]);
  *(u16x4*)(d + (size_t)(n0 + r) * J.K + k0 + c4) = o;
}

// ---------------- bf16 MFMA GEMM ----------------
// C[M,Nc] = act(A'[M,K] @ W[K,Nc] + bias) (+resid); A' = PRE ? A*sigmoid(G) : A
// ACT: 0 none, 1 silu, 2 gelu, 3 = plain bias col<768 / silu+bias2 col>=768.
template <int ACT, bool RES, bool PRE, bool OBF>
__global__ __launch_bounds__(256) void mgemm_k(const void* __restrict__ Av,
                                               const u16* __restrict__ WT,
                                               const float* __restrict__ bias,
                                               const float* __restrict__ resid,
                                               void* __restrict__ Cv, int K, int Nc,
                                               int lda, const float* __restrict__ G,
                                               const float* __restrict__ bias2) {
  __shared__ u16 As[64 * 128];
  __shared__ u16 Bs[64 * 128];
  const int m0 = blockIdx.y * 64, n0 = blockIdx.x * 64;
  const int tid = threadIdx.x;
  const int wave = tid >> 6, lane = tid & 63;
  const int wr = wave >> 1, wc = wave & 1, lr = lane & 15, lg = lane >> 4;
  f32x4 acc[2][2] = {};
  const int srow = tid >> 2, sp = tid & 3;
  for (int k0 = 0; k0 < K; k0 += 128) {
#pragma unroll
    for (int s4 = 0; s4 < 4; s4++) {
      int s = sp * 4 + s4;
      int phys = s ^ (srow & 15);
      if (PRE) {
        const float* ap = (const float*)Av + (size_t)(m0 + srow) * lda + k0 + s * 8;
        const float* gp = G + (size_t)(m0 + srow) * lda + k0 + s * 8;
        float4 a0 = *(const float4*)ap;
        float4 a1 = *(const float4*)(ap + 4);
        float4 g0 = *(const float4*)gp;
        float4 g1 = *(const float4*)(gp + 4);
        short8 vv;
        vv[0] = (short)f2b(a0.x / (1.f + __expf(-g0.x)));
        vv[1] = (short)f2b(a0.y / (1.f + __expf(-g0.y)));
        vv[2] = (short)f2b(a0.z / (1.f + __expf(-g0.z)));
        vv[3] = (short)f2b(a0.w / (1.f + __expf(-g0.w)));
        vv[4] = (short)f2b(a1.x / (1.f + __expf(-g1.x)));
        vv[5] = (short)f2b(a1.y / (1.f + __expf(-g1.y)));
        vv[6] = (short)f2b(a1.z / (1.f + __expf(-g1.z)));
        vv[7] = (short)f2b(a1.w / (1.f + __expf(-g1.w)));
        *(short8*)&As[srow * 128 + phys * 8] = vv;
      } else {
        const u16* Ab = (const u16*)Av;
        short8 v = *(const short8*)(Ab + (size_t)(m0 + srow) * lda + k0 + s * 8);
        *(short8*)&As[srow * 128 + phys * 8] = v;
      }
      short8 w = *(const short8*)(WT + (size_t)(n0 + srow) * K + k0 + s * 8);
      *(short8*)&Bs[srow * 128 + phys * 8] = w;
    }
    __syncthreads();
#pragma unroll
    for (int kk = 0; kk < 4; kk++) {
      int slot = kk * 4 + lg;
      short8 af[2], bf_[2];
#pragma unroll
      for (int i = 0; i < 2; i++) {
        int row = wr * 32 + i * 16 + lr;
        af[i] = *(const short8*)&As[row * 128 + (slot ^ (row & 15)) * 8];
      }
#pragma unroll
      for (int j = 0; j < 2; j++) {
        int row = wc * 32 + j * 16 + lr;
        bf_[j] = *(const short8*)&Bs[row * 128 + (slot ^ (row & 15)) * 8];
      }
#pragma unroll
      for (int i = 0; i < 2; i++)
#pragma unroll
        for (int j = 0; j < 2; j++)
          acc[i][j] = __builtin_amdgcn_mfma_f32_16x16x32_bf16(af[i], bf_[j], acc[i][j], 0, 0, 0);
    }
    __syncthreads();
  }
#pragma unroll
  for (int i = 0; i < 2; i++)
#pragma unroll
    for (int j = 0; j < 2; j++)
#pragma unroll
      for (int rg = 0; rg < 4; rg++) {
        int row = m0 + wr * 32 + i * 16 + lg * 4 + rg;
        int col = n0 + wc * 32 + j * 16 + lr;
        float v;
        if (ACT == 3) {
          float bv = (col < 768) ? bias[col] : bias2[col - 768];
          v = acc[i][j][rg] + bv;
          if (col >= 768) v = v / (1.f + __expf(-v));
        } else {
          v = acc[i][j][rg] + bias[col];
          if (ACT == 1) v = v / (1.f + __expf(-v));
          if (ACT == 2) v = 0.5f * v * (1.f + erff(v * 0.70710678118654752f));
        }
        if (RES) v += resid[(size_t)row * Nc + col];
        if (OBF)
          ((u16*)Cv)[(size_t)row * Nc + col] = f2b(v);
        else
          ((float*)Cv)[(size_t)row * Nc + col] = v;
      }
}

// ---------------- fused attention: full-row softmax, precomputed bias ----------
// grid = B*NH*(N/16); 512 threads = 8 waves; wave handles 2 query rows.
// red[] aliases the dead Ks/Vs region in the epilogue -> LDS 87->51 KB
// -> 3 blocks/CU instead of 1.
__global__ __launch_bounds__(512) void attn_k(const u16* __restrict__ qkv,
                                              const u16* __restrict__ biasb,
                                              float* __restrict__ ctx, int qs) {
  int bid = blockIdx.x;
  int it = bid % (N_ / 16);
  int t2 = bid / (N_ / 16);
  int hh = t2 % NH_;
  int b = t2 / NH_;
  int i0 = it * 16;
  __shared__ __align__(16) u16 KV[2 * 384 * 32];  // Ks | Vs
  __shared__ float Qs[16][32];
  u16* Ks = KV;
  u16* Vs = KV + 384 * 32;
  float (*red)[32][36] = (float(*)[32][36])KV;    // 36 KB <= 48 KB, dead by epilogue
  int tid = threadIdx.x;
  const size_t bb = (size_t)b * N_;
  if (tid < 128) {
    int r = tid >> 3, c4 = (tid & 7) * 4;
    u16x4 q4 = *(const u16x4*)(qkv + (bb + i0 + r) * qs + hh * 32 + c4);
    Qs[r][c4 + 0] = b2f(q4[0]);
    Qs[r][c4 + 1] = b2f(q4[1]);
    Qs[r][c4 + 2] = b2f(q4[2]);
    Qs[r][c4 + 3] = b2f(q4[3]);
  }
#pragma unroll
  for (int m = 0; m < 3; m++) {
    int idx = m * 512 + tid;  // < 1536
    int row = idx >> 2, c = idx & 3;
    int phys = c ^ ((row >> 1) & 3);
    const u16* kb = qkv + (bb + row) * qs + 256 + hh * 32 + c * 8;
    *(short8*)&Ks[row * 32 + phys * 8] = *(const short8*)kb;
    *(short8*)&Vs[row * 32 + phys * 8] = *(const short8*)(kb + 256);
  }
  __syncthreads();
  int wave = tid >> 6, lane = tid & 63;
  int ra = wave * 2;
  const u16* bptr = biasb + (size_t)(b * NH_ + hh) * N_ * N_;
  const int sw = (lane >> 1) & 3;
  float lg[2][6];
  for (int t = 0; t < 6; t++) {
    int j = t * 64 + lane;
    float Kr[32];
#pragma unroll
    for (int c = 0; c < 4; c++) cvt8(&Kr[c * 8], *(const short8*)&Ks[j * 32 + (c ^ sw) * 8]);
#pragma unroll
    for (int r = 0; r < 2; r++) {
      int irow = i0 + ra + r;
      float acc = 0.f;
      const float4* qp = (const float4*)Qs[ra + r];
#pragma unroll
      for (int q = 0; q < 8; q++) {
        float4 qq = qp[q];
        acc += qq.x * Kr[q * 4] + qq.y * Kr[q * 4 + 1] + qq.z * Kr[q * 4 + 2] + qq.w * Kr[q * 4 + 3];
      }
      float bv = b2f(bptr[(size_t)irow * N_ + j]);
      lg[r][t] = acc * INVSC + bv;
    }
  }
  float Ls[2];
#pragma unroll
  for (int r = 0; r < 2; r++) {
    float mx = lg[r][0];
#pragma unroll
    for (int t = 1; t < 6; t++) mx = fmaxf(mx, lg[r][t]);
    mx = wave_max(mx);
    float s = 0.f;
#pragma unroll
    for (int t = 0; t < 6; t++) {
      lg[r][t] = __expf(lg[r][t] - mx);
      s += lg[r][t];
    }
    Ls[r] = wave_sum(s);
  }
  float pc[2][32];
#pragma unroll
  for (int r = 0; r < 2; r++)
#pragma unroll
    for (int k = 0; k < 32; k++) pc[r][k] = 0.f;
  for (int t = 0; t < 6; t++) {
    int j = t * 64 + lane;
    float Vr[32];
#pragma unroll
    for (int c = 0; c < 4; c++) cvt8(&Vr[c * 8], *(const short8*)&Vs[j * 32 + (c ^ sw) * 8]);
#pragma unroll
    for (int r = 0; r < 2; r++)
#pragma unroll
      for (int k = 0; k < 32; k++) pc[r][k] += lg[r][t] * Vr[k];
  }
  int kout = lane >> 1, hf = lane & 1;
#pragma unroll
  for (int r = 0; r < 2; r++) {
    __syncthreads();  // K/V reads done; KV region reused as red
#pragma unroll
    for (int k = 0; k < 32; k++) {
      float v = pc[r][k] + __shfl_xor(pc[r][k], 32);
      if (lane < 32) red[wave][k][lane] = v;
    }
    __syncthreads();
    float s = 0.f;
#pragma unroll
    for (int u = 0; u < 4; u++) {
      float4 q4 = *(const float4*)&red[wave][kout][hf * 16 + u * 4];
      s += q4.x + q4.y + q4.z + q4.w;
    }
    s += __shfl_xor(s, 1);
    if (hf == 0) {
      int row = i0 + ra + r;
      ctx[(bb + row) * H_ + hh * 32 + kout] = s / Ls[r];
    }
  }
}

// ---------------- energy: masked mean over nodes then dot with eh_w ----------------
__global__ __launch_bounds__(256) void energy_k(const float* __restrict__ p2,
                                                const float* __restrict__ mask,
                                                const float* __restrict__ ehw,
                                                const float* __restrict__ ehb,
                                                float* __restrict__ out) {
  int b = blockIdx.x, h = threadIdx.x;
  float s = 0.f, cnt = 0.f;
#pragma unroll 4
  for (int i = 0; i < N_; i++) {
    float m = mask[b * N_ + i] > 0.f ? 1.f : 0.f;
    s += p2[(size_t)(b * N_ + i) * H_ + h] * m;
    cnt += m;
  }
  float val = s * ehw[h];
  __shared__ float red[256];
  red[h] = val;
  __syncthreads();
  for (int st = 128; st > 0; st >>= 1) {
    if (h < st) red[h] += red[h + st];
    __syncthreads();
  }
  if (h == 0) {
    float c = cnt < 1.f ? 1.f : cnt;
    out[b] = red[0] / c + ehb[0];
  }
}

extern "C" void kernel_launch(void* const* d_in, const int* in_sizes, int n_in,
                              void* d_out, int out_size, void* d_ws, size_t ws_size,
                              hipStream_t stream) {
  const int* node_idx = (const int*)d_in[0];
  const float* positions = (const float*)d_in[1];
  const float* mask = (const float*)d_in[2];
  const float* emb = (const float*)d_in[3];
  const float* ln1_g = (const float*)d_in[4];
  const float* ln1_b = (const float*)d_in[5];
  const float* qkv_w = (const float*)d_in[6];
  const float* qkv_b = (const float*)d_in[7];
  const float* out_w = (const float*)d_in[8];
  const float* out_b = (const float*)d_in[9];
  const float* rb_w1 = (const float*)d_in[10];
  const float* rb_b1 = (const float*)d_in[11];
  const float* rb_w2 = (const float*)d_in[12];
  const float* rb_b2 = (const float*)d_in[13];
  const float* gate_w1 = (const float*)d_in[14];
  const float* gate_b1 = (const float*)d_in[15];
  const float* gate_w2 = (const float*)d_in[16];
  const float* gate_b2 = (const float*)d_in[17];
  const float* ln2_g = (const float*)d_in[18];
  const float* ln2_b = (const float*)d_in[19];
  const float* ff_w1 = (const float*)d_in[20];
  const float* ff_b1 = (const float*)d_in[21];
  const float* ff_w2 = (const float*)d_in[22];
  const float* ff_b2 = (const float*)d_in[23];
  const float* pool_g = (const float*)d_in[24];
  const float* pool_beta = (const float*)d_in[25];
  const float* pool_w = (const float*)d_in[26];
  const float* pool_b = (const float*)d_in[27];
  const float* eh_w = (const float*)d_in[28];
  const float* eh_b = (const float*)d_in[29];
  float* eout = (float*)d_out;

  // workspace layout (bytes)
  char* W8 = (char*)d_ws;
  float* x = (float*)(W8 + 0);              // 1572864 B (M x 256 f32)
  u16* qgb = (u16*)(W8 + 1572864);          // 3145728 B (M x 1024 bf16: q|k|v|g1)
  float* ctx = (float*)(W8 + 4718592);      // 1572864 B
  float* g2 = (float*)(W8 + 6291456);       // 1572864 B
  u16* hb = (u16*)(W8 + 7864320);           // 786432 B  (M x 256 bf16)
  u16* ffb = (u16*)(W8 + 8650752);          // 1572864 B (M x 512 bf16)
  float* distm = (float*)(W8 + 10223616);   // 2359296 B
  float* tbl2 = (float*)(W8 + 12582912);    // 4099 x 32 x 4 = 524672 B (t-major)
  u16* wt = (u16*)(W8 + 13631488);          // 5373952 B
  u16* wt_qg = wt;                  // 4 x 1024 x 256
  u16* wt_out = wt + 1048576;       // 4 x 256 x 256
  u16* wt_g2 = wt + 1310720;
  u16* wt_f1 = wt + 1572864;        // 4 x 512 x 256
  u16* wt_f2 = wt + 2097152;        // 4 x 256 x 512
  u16* wt_p = wt + 2621440;         // 256 x 256
  u16* biasb = (u16*)(W8 + 19005440);       // 4 x 9437184 B ([l][b][h][i][j] bf16)
  const size_t bias_lstride = (size_t)B_ * NH_ * N_ * N_;

  // ---- setup ----
  embed_k<<<M_ * H_ / 256, 256, 0, stream>>>(node_idx, mask, emb, x);
  dist_k<<<B_ * N_ * N_ / 256, 256, 0, stream>>>(positions, mask, distm);
  table_k<<<dim3(65, L_), 256, 0, stream>>>(rb_w1, rb_b1, rb_w2, rb_b2, tbl2);
  {
    TrJobs jobs;
    jobs.j[0] = {qkv_w, wt_qg, 256, 768, 24, 8, 4, 0, 262144};
    jobs.j[1] = {gate_w1, wt_qg + 768 * 256, 256, 256, 8, 8, 4, 768, 262144};
    jobs.j[2] = {out_w, wt_out, 256, 256, 8, 8, 4, 1024, 65536};
    jobs.j[3] = {gate_w2, wt_g2, 256, 256, 8, 8, 4, 1280, 65536};
    jobs.j[4] = {ff_w1, wt_f1, 256, 512, 16, 8, 4, 1536, 131072};
    jobs.j[5] = {ff_w2, wt_f2, 512, 256, 8, 16, 4, 2048, 131072};
    jobs.j[6] = {pool_w, wt_p, 256, 256, 8, 8, 1, 2560, 65536};
    tr_all_k<<<2624, 256, 0, stream>>>(jobs);
  }
  bias_all2_k<<<B_ * N_ * N_ / 256, 256, 0, stream>>>(distm, tbl2, biasb);

  for (int l = 0; l < L_; l++) {
    const float* qb = qkv_b + (size_t)l * 3 * H_;
    const float* ob = out_b + (size_t)l * H_;
    const float* gb1 = gate_b1 + (size_t)l * H_;
    const float* gb2 = gate_b2 + (size_t)l * H_;
    const float* fb1 = ff_b1 + (size_t)l * 2 * H_;
    const float* fb2 = ff_b2 + (size_t)l * H_;
    u16* wqg = wt_qg + (size_t)l * 1024 * 256;
    u16* wo = wt_out + (size_t)l * 256 * 256;
    u16* wg2 = wt_g2 + (size_t)l * 256 * 256;
    u16* wf1 = wt_f1 + (size_t)l * 512 * 256;
    u16* wf2 = wt_f2 + (size_t)l * 256 * 512;

    // hb = bf16(LN1(x))
    ln_k<<<M_ / 4, 256, 0, stream>>>(x, ln1_g + l * H_, ln1_b + l * H_, hb);
    // qgb = hb @ [qkv_w | gate_w1] (+biases, silu on g1 cols) -> bf16
    mgemm_k<3, false, false, true><<<dim3(16, 24), 256, 0, stream>>>(
        hb, wqg, qb, nullptr, qgb, 256, 1024, 256, nullptr, gb1);
    // ctx = attention(qgb, biasb[l])
    attn_k<<<B_ * NH_ * (N_ / 16), 512, 0, stream>>>(
        qgb, biasb + (size_t)l * bias_lstride, ctx, 1024);
    // g2 = g1 @ gate_w2 + gate_b2 (fp32 out); g1 = qgb cols 768..1023
    mgemm_k<0, false, false, false><<<dim3(4, 24), 256, 0, stream>>>(
        (const void*)(qgb + 768), wg2, gb2, nullptr, g2, 256, 256, 1024, nullptr, nullptr);
    // x = x + bf16(ctx * sigmoid(g2)) @ out_w + out_b
    mgemm_k<0, true, true, false><<<dim3(4, 24), 256, 0, stream>>>(
        ctx, wo, ob, x, x, 256, 256, 256, g2, nullptr);
    // hb = bf16(LN2(x))
    ln_k<<<M_ / 4, 256, 0, stream>>>(x, ln2_g + l * H_, ln2_b + l * H_, hb);
    // ffb = bf16(gelu(hb @ ff_w1 + ff_b1))
    mgemm_k<2, false, false, true><<<dim3(8, 24), 256, 0, stream>>>(
        hb, wf1, fb1, nullptr, ffb, 256, 512, 256, nullptr, nullptr);
    // x = x + ffb @ ff_w2 + ff_b2
    mgemm_k<0, true, false, false><<<dim3(4, 24), 256, 0, stream>>>(
        ffb, wf2, fb2, x, x, 512, 256, 512, nullptr, nullptr);
  }

  // pooling head
  ln_k<<<M_ / 4, 256, 0, stream>>>(x, pool_g, pool_beta, hb);
  mgemm_k<1, false, false, false><<<dim3(4, 24), 256, 0, stream>>>(
      hb, wt_p, pool_b, nullptr, ctx, 256, 256, 256, nullptr, nullptr);
  energy_k<<<B_, 256, 0, stream>>>(ctx, mask, eh_w, eh_b, eout);
}

// Round 10
// 307.855 us; speedup vs baseline: 1.6802x; 1.2595x over previous
//
#include <hip/hip_runtime.h>
#include <hip/hip_bf16.h>
#include <math.h>

// Problem constants (hardcoded from reference)
constexpr int B_ = 4, N_ = 384, H_ = 256, NH_ = 8, DD_ = 32, L_ = 4;
constexpr int M_ = B_ * N_;          // 1536 node rows
constexpr float CUT = 5.0f;
constexpr float PI_ = 3.14159265358979323846f;
constexpr float INVSC = 0.17677669529663687f;  // 1/sqrt(32)
constexpr int TBL_N = 4096;
constexpr int TBL_STRIDE = 4098;

typedef __attribute__((ext_vector_type(8))) short short8;
typedef __attribute__((ext_vector_type(4))) float f32x4;
typedef __attribute__((ext_vector_type(4))) unsigned short u16x4;
using u16 = unsigned short;

__device__ __forceinline__ u16 f2b(float f) {
  __hip_bfloat16 h = __float2bfloat16(f);
  return *reinterpret_cast<u16*>(&h);
}
__device__ __forceinline__ float b2f(u16 u) {
  __hip_bfloat16 h;
  *reinterpret_cast<u16*>(&h) = u;
  return __bfloat162float(h);
}

__device__ __forceinline__ float wave_sum(float v) {
#pragma unroll
  for (int s = 1; s < 64; s <<= 1) v += __shfl_xor(v, s);
  return v;
}

// ---------------- embed: x = emb[idx] * maskb ----------------
__global__ __launch_bounds__(256) void embed_k(const int* __restrict__ idx,
                                               const float* __restrict__ mask,
                                               const float* __restrict__ emb,
                                               float* __restrict__ X) {
  int e = blockIdx.x * 256 + threadIdx.x;
  int mrow = e >> 8, c = e & 255;
  float mb = mask[mrow] > 0.f ? 1.f : 0.f;
  X[e] = emb[idx[mrow] * H_ + c] * mb;
}

// ---------------- dist: masked distances ----------------
__global__ __launch_bounds__(256) void dist_k(const float* __restrict__ pos,
                                              const float* __restrict__ mask,
                                              float* __restrict__ distm) {
  int e = blockIdx.x * 256 + threadIdx.x;
  int j = e % N_;
  int t = e / N_;
  int i = t % N_;
  int b = t / N_;
  float mi = mask[b * N_ + i], mj = mask[b * N_ + j];
  const float* pi = pos + (size_t)(b * N_ + i) * 3;
  const float* pj = pos + (size_t)(b * N_ + j) * 3;
  float dx = pi[0] - pj[0] + 1e-9f;
  float dy = pi[1] - pj[1] + 1e-9f;
  float dz = pi[2] - pj[2] + 1e-9f;
  float d = sqrtf(dx * dx + dy * dy + dz * dz);
  distm[e] = (mi > 0.f && mj > 0.f) ? d : 1e30f;
}

// ---------------- bias table (t-major output): tbl2[t][l*8+h] ----------------
__global__ __launch_bounds__(256) void table_k(const float* __restrict__ rb_w1,
                                               const float* __restrict__ rb_b1,
                                               const float* __restrict__ rb_w2,
                                               const float* __restrict__ rb_b2,
                                               float* __restrict__ tbl2) {
  constexpr int TT = 64;
  int l = blockIdx.y;
  int t0 = blockIdx.x * TT;
  int tid = threadIdx.x;
  __shared__ float sfA[TT][32];
  __shared__ float hbA[TT][260];
#pragma unroll
  for (int m = 0; m < 8; m++) {
    int idx = m * 256 + tid;
    int tl = idx >> 5, k = idx & 31;
    int t = t0 + tl;
    float d = (t <= TBL_N) ? (t * (CUT / (float)TBL_N)) : 1.7320508075688772e-9f;
    float ang = PI_ * (k + 1) * d * (1.f / CUT);
    sfA[tl][k] = sinf(ang) / (d + 1e-6f);
  }
  __syncthreads();
  float w1c[32];
  const float* w1 = rb_w1 + (size_t)l * DD_ * H_;
#pragma unroll
  for (int k = 0; k < 32; k++) w1c[k] = w1[k * H_ + tid];
  float b1v = rb_b1[l * H_ + tid];
  for (int tl = 0; tl < TT; tl++) {
    float pre = b1v;
    const float4* sfp = (const float4*)sfA[tl];
#pragma unroll
    for (int kq = 0; kq < 8; kq++) {
      float4 s4 = sfp[kq];
      pre += s4.x * w1c[kq * 4] + s4.y * w1c[kq * 4 + 1] + s4.z * w1c[kq * 4 + 2] +
             s4.w * w1c[kq * 4 + 3];
    }
    hbA[tl][tid] = pre / (1.f + __expf(-pre));
  }
  __syncthreads();
  const float* w2 = rb_w2 + (size_t)l * H_ * NH_;
  int o = tid & 7;
  float b2v = rb_b2[l * NH_ + o];
#pragma unroll
  for (int half = 0; half < 2; half++) {
    int tl = (tid >> 3) + half * 32;
    float acc = b2v;
    const float4* hp = (const float4*)hbA[tl];
#pragma unroll 4
    for (int hq = 0; hq < 64; hq++) {
      float4 h4 = hp[hq];
      acc += h4.x * w2[(hq * 4 + 0) * NH_ + o] + h4.y * w2[(hq * 4 + 1) * NH_ + o] +
             h4.z * w2[(hq * 4 + 2) * NH_ + o] + h4.w * w2[(hq * 4 + 3) * NH_ + o];
    }
    int t = t0 + tl;
    if (t <= TBL_STRIDE) tbl2[(size_t)t * 32 + l * NH_ + o] = acc;
  }
}

// ---------------- all-layer bias tensors, vectorized row-lerp ----------------
__global__ __launch_bounds__(256) void bias_all2_k(const float* __restrict__ distm,
                                                   const float* __restrict__ tbl2,
                                                   u16* __restrict__ biasb) {
  int e = blockIdx.x * 256 + threadIdx.x;  // < B*N*N
  int j = e % N_;
  int t = e / N_;
  int i = t % N_;
  int b = t / N_;
  float d = distm[e];
  size_t plane = (size_t)N_ * N_;
  size_t obase = (size_t)b * NH_ * plane + (size_t)i * N_ + j;
  size_t lstride = (size_t)B_ * NH_ * plane;
  if (d <= CUT) {
    int ixrow;
    float fr;
    if (i == j) {
      ixrow = TBL_N + 1;
      fr = 0.f;
    } else {
      float u = d * ((float)TBL_N / CUT);
      int ix = (int)u;
      ix = ix > TBL_N - 1 ? TBL_N - 1 : ix;
      fr = u - (float)ix;
      ixrow = ix;
    }
    const float4* r0 = (const float4*)(tbl2 + (size_t)ixrow * 32);
    const float4* r1 = (const float4*)(tbl2 + (size_t)(ixrow + 1) * 32);
    float4 a0[8], a1[8];
#pragma unroll
    for (int q = 0; q < 8; q++) {
      a0[q] = r0[q];
      a1[q] = r1[q];
    }
    float w0 = 1.f - fr;
#pragma unroll
    for (int q = 0; q < 8; q++) {
      float v0[4] = {a0[q].x, a0[q].y, a0[q].z, a0[q].w};
      float v1[4] = {a1[q].x, a1[q].y, a1[q].z, a1[q].w};
#pragma unroll
      for (int c = 0; c < 4; c++) {
        int lh = q * 4 + c;
        int l = lh >> 3, h = lh & 7;
        float v = v0[c] * w0 + v1[c] * fr;
        biasb[(size_t)l * lstride + obase + (size_t)h * plane] = f2b(v);
      }
    }
  } else {
#pragma unroll
    for (int lh = 0; lh < 32; lh++) {
      int l = lh >> 3, h = lh & 7;
      biasb[(size_t)l * lstride + obase + (size_t)h * plane] = 0xFF80;  // -inf
    }
  }
}

// ---------------- LayerNorm (row of 256) -> bf16 output ----------------
__global__ __launch_bounds__(256) void ln_k(const float* __restrict__ X,
                                            const float* __restrict__ g,
                                            const float* __restrict__ bta,
                                            u16* __restrict__ O) {
  int wave = threadIdx.x >> 6, lane = threadIdx.x & 63;
  int row = blockIdx.x * 4 + wave;
  const float* xr = X + (size_t)row * H_;
  float4 v = *(const float4*)(xr + lane * 4);
  float s = v.x + v.y + v.z + v.w;
  s = wave_sum(s);
  float m = s * (1.f / H_);
  float dx = v.x - m, dy = v.y - m, dz = v.z - m, dw = v.w - m;
  float vs = dx * dx + dy * dy + dz * dz + dw * dw;
  vs = wave_sum(vs);
  float rs = rsqrtf(vs * (1.f / H_) + 1e-5f);
  float4 gg = *(const float4*)(g + lane * 4);
  float4 bb = *(const float4*)(bta + lane * 4);
  u16x4 o;
  o[0] = f2b(dx * rs * gg.x + bb.x);
  o[1] = f2b(dy * rs * gg.y + bb.y);
  o[2] = f2b(dz * rs * gg.z + bb.z);
  o[3] = f2b(dw * rs * gg.w + bb.w);
  *(u16x4*)(O + (size_t)row * H_ + lane * 4) = o;
}

// ---------------- combined weight transpose: W[K][N] fp32 -> WT[N][K] bf16 --------
struct TrJob {
  const float* src;
  u16* dst;
  int K, N, nx, ny, nz, base, dstride;
};
struct TrJobs {
  TrJob j[7];
};
__global__ __launch_bounds__(256) void tr_all_k(TrJobs jobs) {
  __shared__ float t[32][33];
  int bid = blockIdx.x;
  int ji = 0;
#pragma unroll
  for (int q = 1; q < 7; q++)
    if (bid >= jobs.j[q].base) ji = q;
  const TrJob& J = jobs.j[ji];
  int local = bid - J.base;
  int z = local / (J.nx * J.ny);
  int r2 = local % (J.nx * J.ny);
  int ky = r2 / J.nx, kx = r2 % J.nx;
  int n0 = kx * 32, k0 = ky * 32;
  const float* s = J.src + (size_t)z * J.K * J.N;
  u16* d = J.dst + (size_t)z * J.dstride;
  int tid = threadIdx.x;
  int r = tid >> 3, c4 = (tid & 7) * 4;
  float4 v = *(const float4*)(s + (size_t)(k0 + r) * J.N + n0 + c4);
  t[r][c4 + 0] = v.x;
  t[r][c4 + 1] = v.y;
  t[r][c4 + 2] = v.z;
  t[r][c4 + 3] = v.w;
  __syncthreads();
  u16x4 o;
  o[0] = f2b(t[c4 + 0][r]);
  o[1] = f2b(t[c4 + 1][r]);
  o[2] = f2b(t[c4 + 2][r]);
  o[3] = f2b(t[c4 + 3][r]);
  *(u16x4*)(d + (size_t)(n0 + r) * J.K + k0 + c4) = o;
}

// ---------------- bf16 MFMA GEMM ----------------
// C[M,Nc] = act(A'[M,K] @ W[K,Nc] + bias) (+resid); A' = PRE ? A*sigmoid(G) : A
// ACT: 0 none, 1 silu, 2 gelu, 3 = plain bias col<768 / silu+bias2 col>=768.
template <int ACT, bool RES, bool PRE, bool OBF>
__global__ __launch_bounds__(256) void mgemm_k(const void* __restrict__ Av,
                                               const u16* __restrict__ WT,
                                               const float* __restrict__ bias,
                                               const float* __restrict__ resid,
                                               void* __restrict__ Cv, int K, int Nc,
                                               int lda, const float* __restrict__ G,
                                               const float* __restrict__ bias2) {
  __shared__ u16 As[64 * 128];
  __shared__ u16 Bs[64 * 128];
  const int m0 = blockIdx.y * 64, n0 = blockIdx.x * 64;
  const int tid = threadIdx.x;
  const int wave = tid >> 6, lane = tid & 63;
  const int wr = wave >> 1, wc = wave & 1, lr = lane & 15, lg = lane >> 4;
  f32x4 acc[2][2] = {};
  const int srow = tid >> 2, sp = tid & 3;
  for (int k0 = 0; k0 < K; k0 += 128) {
#pragma unroll
    for (int s4 = 0; s4 < 4; s4++) {
      int s = sp * 4 + s4;
      int phys = s ^ (srow & 15);
      if (PRE) {
        const float* ap = (const float*)Av + (size_t)(m0 + srow) * lda + k0 + s * 8;
        const float* gp = G + (size_t)(m0 + srow) * lda + k0 + s * 8;
        float4 a0 = *(const float4*)ap;
        float4 a1 = *(const float4*)(ap + 4);
        float4 g0 = *(const float4*)gp;
        float4 g1 = *(const float4*)(gp + 4);
        short8 vv;
        vv[0] = (short)f2b(a0.x / (1.f + __expf(-g0.x)));
        vv[1] = (short)f2b(a0.y / (1.f + __expf(-g0.y)));
        vv[2] = (short)f2b(a0.z / (1.f + __expf(-g0.z)));
        vv[3] = (short)f2b(a0.w / (1.f + __expf(-g0.w)));
        vv[4] = (short)f2b(a1.x / (1.f + __expf(-g1.x)));
        vv[5] = (short)f2b(a1.y / (1.f + __expf(-g1.y)));
        vv[6] = (short)f2b(a1.z / (1.f + __expf(-g1.z)));
        vv[7] = (short)f2b(a1.w / (1.f + __expf(-g1.w)));
        *(short8*)&As[srow * 128 + phys * 8] = vv;
      } else {
        const u16* Ab = (const u16*)Av;
        short8 v = *(const short8*)(Ab + (size_t)(m0 + srow) * lda + k0 + s * 8);
        *(short8*)&As[srow * 128 + phys * 8] = v;
      }
      short8 w = *(const short8*)(WT + (size_t)(n0 + srow) * K + k0 + s * 8);
      *(short8*)&Bs[srow * 128 + phys * 8] = w;
    }
    __syncthreads();
#pragma unroll
    for (int kk = 0; kk < 4; kk++) {
      int slot = kk * 4 + lg;
      short8 af[2], bf_[2];
#pragma unroll
      for (int i = 0; i < 2; i++) {
        int row = wr * 32 + i * 16 + lr;
        af[i] = *(const short8*)&As[row * 128 + (slot ^ (row & 15)) * 8];
      }
#pragma unroll
      for (int j = 0; j < 2; j++) {
        int row = wc * 32 + j * 16 + lr;
        bf_[j] = *(const short8*)&Bs[row * 128 + (slot ^ (row & 15)) * 8];
      }
#pragma unroll
      for (int i = 0; i < 2; i++)
#pragma unroll
        for (int j = 0; j < 2; j++)
          acc[i][j] = __builtin_amdgcn_mfma_f32_16x16x32_bf16(af[i], bf_[j], acc[i][j], 0, 0, 0);
    }
    __syncthreads();
  }
#pragma unroll
  for (int i = 0; i < 2; i++)
#pragma unroll
    for (int j = 0; j < 2; j++)
#pragma unroll
      for (int rg = 0; rg < 4; rg++) {
        int row = m0 + wr * 32 + i * 16 + lg * 4 + rg;
        int col = n0 + wc * 32 + j * 16 + lr;
        float v;
        if (ACT == 3) {
          float bv = (col < 768) ? bias[col] : bias2[col - 768];
          v = acc[i][j][rg] + bv;
          if (col >= 768) v = v / (1.f + __expf(-v));
        } else {
          v = acc[i][j][rg] + bias[col];
          if (ACT == 1) v = v / (1.f + __expf(-v));
          if (ACT == 2) v = 0.5f * v * (1.f + erff(v * 0.70710678118654752f));
        }
        if (RES) v += resid[(size_t)row * Nc + col];
        if (OBF)
          ((u16*)Cv)[(size_t)row * Nc + col] = f2b(v);
        else
          ((float*)Cv)[(size_t)row * Nc + col] = v;
      }
}

// ---------------- MFMA fused attention ----------------
// grid dim3(12, NH, B); 256 threads = 4 waves. Block: 32 query rows, one head.
// wave (rh = w&1, kh = w>>1): rows 16*rh..+15, keys 192*kh..+191.
// All operands staged FRAGMENT-LINEAR in LDS (Frag[tile][lane][8] bf16) so each
// MFMA operand is one conflict-free ds_read_b128 of a contiguous 1KB stripe.
// Fragment conventions (m89-verified, same as mgemm_k):
//   A/B: lane holds row (lane&15), k-elems 8*(lane>>4)..+7
//   C:   col = lane&15, row = 4*(lane>>4)+reg
// FragP reuses FragK (dead after QK); pbuf reuses FragV (dead after PV).
__global__ __launch_bounds__(256) void attn_mf(const u16* __restrict__ qkv,
                                               const u16* __restrict__ biasb,
                                               float* __restrict__ ctx, int qs) {
  __shared__ __align__(16) u16 FragQ[2 * 64 * 8];    // 2 KB
  __shared__ __align__(16) u16 FragK[24 * 64 * 8];   // 24 KB (aliased by FragP)
  __shared__ __align__(16) u16 FragV[24 * 64 * 8];   // 24 KB (aliased by pbuf)
  __shared__ float smax[2][32];
  __shared__ float ssum[2][32];
  u16* FragP = FragK;
  float* pbuf = (float*)FragV;

  const int it = blockIdx.x, hh = blockIdx.y, b = blockIdx.z;
  const int i0 = it * 32;
  const int tid = threadIdx.x;
  const size_t bb = (size_t)b * N_;

  // ---- stage Q (rows i0..i0+31) ----
  if (tid < 128) {
    int q = tid >> 2, dc = tid & 3;
    short8 v = *(const short8*)(qkv + (bb + i0 + q) * qs + hh * 32 + dc * 8);
    *(short8*)&FragQ[(((q >> 4) * 64) + (q & 15) + 16 * dc) * 8] = v;
  }
  // ---- stage K (frag-linear) and V (scatter-transposed frag-linear) ----
#pragma unroll
  for (int m = 0; m < 6; m++) {
    int idx = m * 256 + tid;
    int key = idx >> 2, dc = idx & 3;
    const u16* kb = qkv + (bb + key) * qs + 256 + hh * 32 + dc * 8;
    short8 kv = *(const short8*)kb;
    *(short8*)&FragK[(((key >> 4) * 64) + (key & 15) + 16 * dc) * 8] = kv;
    short8 vv = *(const short8*)(kb + 256);
    int kc = key >> 5, sub = (key >> 3) & 3, kj = key & 7;
#pragma unroll
    for (int j = 0; j < 8; j++) {
      int d = dc * 8 + j;
      FragV[(((kc * 2 + (d >> 4)) * 64) + (d & 15) + 16 * sub) * 8 + kj] = (u16)vv[j];
    }
  }
  __syncthreads();  // #0: stages ready

  const int wave = tid >> 6, lane = tid & 63;
  const int rh = wave & 1, kh = wave >> 1;
  const int g = lane >> 4, c = lane & 15;
  const u16* bptr = biasb + (size_t)(b * NH_ + hh) * N_ * N_;

  // ---- QK^T: 12 MFMAs over this wave's key half ----
  short8 qf = *(const short8*)&FragQ[(rh * 64 + lane) * 8];
  f32x4 sc[12];
#pragma unroll
  for (int t = 0; t < 12; t++) {
    int T = kh * 12 + t;
    short8 kf = *(const short8*)&FragK[(T * 64 + lane) * 8];
    f32x4 z = {0.f, 0.f, 0.f, 0.f};
    sc[t] = __builtin_amdgcn_mfma_f32_16x16x32_bf16(qf, kf, z, 0, 0, 0);
    int key = 16 * T + c;
#pragma unroll
    for (int reg = 0; reg < 4; reg++) {
      int row = i0 + 16 * rh + 4 * g + reg;
      float bv = b2f(bptr[(size_t)row * N_ + key]);
      sc[t][reg] = sc[t][reg] * INVSC + bv;
    }
  }
  // ---- softmax: per-lane partial max over 12 tiles, 16-lane reduce, cross-wave ----
  float mx[4];
#pragma unroll
  for (int reg = 0; reg < 4; reg++) {
    float m = sc[0][reg];
#pragma unroll
    for (int t = 1; t < 12; t++) m = fmaxf(m, sc[t][reg]);
#pragma unroll
    for (int s = 1; s < 16; s <<= 1) m = fmaxf(m, __shfl_xor(m, s));
    mx[reg] = m;
  }
  if (c == 0) {
#pragma unroll
    for (int reg = 0; reg < 4; reg++) smax[kh][16 * rh + 4 * g + reg] = mx[reg];
  }
  __syncthreads();  // #1: smax ready (all FragK reads done before here)
  float sm[4];
#pragma unroll
  for (int reg = 0; reg < 4; reg++) {
    float M = fmaxf(smax[0][16 * rh + 4 * g + reg], smax[1][16 * rh + 4 * g + reg]);
    float s = 0.f;
#pragma unroll
    for (int t = 0; t < 12; t++) {
      float p = __expf(sc[t][reg] - M);
      sc[t][reg] = p;
      s += p;
    }
    sm[reg] = s;
  }
#pragma unroll
  for (int reg = 0; reg < 4; reg++) {
#pragma unroll
    for (int s = 1; s < 16; s <<= 1) sm[reg] += __shfl_xor(sm[reg], s);
  }
  if (c == 0) {
#pragma unroll
    for (int reg = 0; reg < 4; reg++) ssum[kh][16 * rh + 4 * g + reg] = sm[reg];
  }
  // ---- write P (bf16) to FragP in A-fragment order (over dead FragK) ----
#pragma unroll
  for (int t = 0; t < 12; t++) {
    int T = kh * 12 + t;
    int kc = T >> 1;
    int sub = (2 * T + (c >> 3)) & 3;
#pragma unroll
    for (int reg = 0; reg < 4; reg++) {
      FragP[((rh * 12 + kc) * 64 + (4 * g + reg) + 16 * sub) * 8 + (c & 7)] =
          f2b(sc[t][reg]);
    }
  }
  __syncthreads();  // #2: ssum ready (and FragP writes ordered before PV of other waves)
  float Ls[4];
#pragma unroll
  for (int reg = 0; reg < 4; reg++)
    Ls[reg] = ssum[0][16 * rh + 4 * g + reg] + ssum[1][16 * rh + 4 * g + reg];

  // ---- PV: 6 key-chunks x 2 d-halves over this wave's key half ----
  f32x4 pcc[2] = {};
#pragma unroll
  for (int t = 0; t < 6; t++) {
    int kc = kh * 6 + t;
    short8 pf = *(const short8*)&FragP[((rh * 12 + kc) * 64 + lane) * 8];
#pragma unroll
    for (int nh = 0; nh < 2; nh++) {
      short8 vf = *(const short8*)&FragV[((kc * 2 + nh) * 64 + lane) * 8];
      pcc[nh] = __builtin_amdgcn_mfma_f32_16x16x32_bf16(pf, vf, pcc[nh], 0, 0, 0);
    }
  }
  __syncthreads();  // #3: all PV done, FragV dead -> pbuf
  if (kh == 1) {
#pragma unroll
    for (int nh = 0; nh < 2; nh++)
#pragma unroll
      for (int reg = 0; reg < 4; reg++)
        pbuf[rh * 512 + (4 * g + reg) * 32 + nh * 16 + c] = pcc[nh][reg];
  }
  __syncthreads();  // #4
  if (kh == 0) {
#pragma unroll
    for (int nh = 0; nh < 2; nh++)
#pragma unroll
      for (int reg = 0; reg < 4; reg++) {
        float v = pcc[nh][reg] + pbuf[rh * 512 + (4 * g + reg) * 32 + nh * 16 + c];
        int row = i0 + 16 * rh + 4 * g + reg;
        ctx[(bb + row) * H_ + hh * 32 + nh * 16 + c] = v / Ls[reg];
      }
  }
}

// ---------------- energy: masked mean over nodes then dot with eh_w ----------------
__global__ __launch_bounds__(256) void energy_k(const float* __restrict__ p2,
                                                const float* __restrict__ mask,
                                                const float* __restrict__ ehw,
                                                const float* __restrict__ ehb,
                                                float* __restrict__ out) {
  int b = blockIdx.x, h = threadIdx.x;
  float s = 0.f, cnt = 0.f;
#pragma unroll 4
  for (int i = 0; i < N_; i++) {
    float m = mask[b * N_ + i] > 0.f ? 1.f : 0.f;
    s += p2[(size_t)(b * N_ + i) * H_ + h] * m;
    cnt += m;
  }
  float val = s * ehw[h];
  __shared__ float red[256];
  red[h] = val;
  __syncthreads();
  for (int st = 128; st > 0; st >>= 1) {
    if (h < st) red[h] += red[h + st];
    __syncthreads();
  }
  if (h == 0) {
    float c = cnt < 1.f ? 1.f : cnt;
    out[b] = red[0] / c + ehb[0];
  }
}

extern "C" void kernel_launch(void* const* d_in, const int* in_sizes, int n_in,
                              void* d_out, int out_size, void* d_ws, size_t ws_size,
                              hipStream_t stream) {
  const int* node_idx = (const int*)d_in[0];
  const float* positions = (const float*)d_in[1];
  const float* mask = (const float*)d_in[2];
  const float* emb = (const float*)d_in[3];
  const float* ln1_g = (const float*)d_in[4];
  const float* ln1_b = (const float*)d_in[5];
  const float* qkv_w = (const float*)d_in[6];
  const float* qkv_b = (const float*)d_in[7];
  const float* out_w = (const float*)d_in[8];
  const float* out_b = (const float*)d_in[9];
  const float* rb_w1 = (const float*)d_in[10];
  const float* rb_b1 = (const float*)d_in[11];
  const float* rb_w2 = (const float*)d_in[12];
  const float* rb_b2 = (const float*)d_in[13];
  const float* gate_w1 = (const float*)d_in[14];
  const float* gate_b1 = (const float*)d_in[15];
  const float* gate_w2 = (const float*)d_in[16];
  const float* gate_b2 = (const float*)d_in[17];
  const float* ln2_g = (const float*)d_in[18];
  const float* ln2_b = (const float*)d_in[19];
  const float* ff_w1 = (const float*)d_in[20];
  const float* ff_b1 = (const float*)d_in[21];
  const float* ff_w2 = (const float*)d_in[22];
  const float* ff_b2 = (const float*)d_in[23];
  const float* pool_g = (const float*)d_in[24];
  const float* pool_beta = (const float*)d_in[25];
  const float* pool_w = (const float*)d_in[26];
  const float* pool_b = (const float*)d_in[27];
  const float* eh_w = (const float*)d_in[28];
  const float* eh_b = (const float*)d_in[29];
  float* eout = (float*)d_out;

  // workspace layout (bytes)
  char* W8 = (char*)d_ws;
  float* x = (float*)(W8 + 0);              // 1572864 B (M x 256 f32)
  u16* qgb = (u16*)(W8 + 1572864);          // 3145728 B (M x 1024 bf16: q|k|v|g1)
  float* ctx = (float*)(W8 + 4718592);      // 1572864 B
  float* g2 = (float*)(W8 + 6291456);       // 1572864 B
  u16* hb = (u16*)(W8 + 7864320);           // 786432 B  (M x 256 bf16)
  u16* ffb = (u16*)(W8 + 8650752);          // 1572864 B (M x 512 bf16)
  float* distm = (float*)(W8 + 10223616);   // 2359296 B
  float* tbl2 = (float*)(W8 + 12582912);    // 4099 x 32 x 4 = 524672 B (t-major)
  u16* wt = (u16*)(W8 + 13631488);          // 5373952 B
  u16* wt_qg = wt;                  // 4 x 1024 x 256
  u16* wt_out = wt + 1048576;       // 4 x 256 x 256
  u16* wt_g2 = wt + 1310720;
  u16* wt_f1 = wt + 1572864;        // 4 x 512 x 256
  u16* wt_f2 = wt + 2097152;        // 4 x 256 x 512
  u16* wt_p = wt + 2621440;         // 256 x 256
  u16* biasb = (u16*)(W8 + 19005440);       // 4 x 9437184 B ([l][b][h][i][j] bf16)
  const size_t bias_lstride = (size_t)B_ * NH_ * N_ * N_;

  // ---- setup ----
  embed_k<<<M_ * H_ / 256, 256, 0, stream>>>(node_idx, mask, emb, x);
  dist_k<<<B_ * N_ * N_ / 256, 256, 0, stream>>>(positions, mask, distm);
  table_k<<<dim3(65, L_), 256, 0, stream>>>(rb_w1, rb_b1, rb_w2, rb_b2, tbl2);
  {
    TrJobs jobs;
    jobs.j[0] = {qkv_w, wt_qg, 256, 768, 24, 8, 4, 0, 262144};
    jobs.j[1] = {gate_w1, wt_qg + 768 * 256, 256, 256, 8, 8, 4, 768, 262144};
    jobs.j[2] = {out_w, wt_out, 256, 256, 8, 8, 4, 1024, 65536};
    jobs.j[3] = {gate_w2, wt_g2, 256, 256, 8, 8, 4, 1280, 65536};
    jobs.j[4] = {ff_w1, wt_f1, 256, 512, 16, 8, 4, 1536, 131072};
    jobs.j[5] = {ff_w2, wt_f2, 512, 256, 8, 16, 4, 2048, 131072};
    jobs.j[6] = {pool_w, wt_p, 256, 256, 8, 8, 1, 2560, 65536};
    tr_all_k<<<2624, 256, 0, stream>>>(jobs);
  }
  bias_all2_k<<<B_ * N_ * N_ / 256, 256, 0, stream>>>(distm, tbl2, biasb);

  for (int l = 0; l < L_; l++) {
    const float* qb = qkv_b + (size_t)l * 3 * H_;
    const float* ob = out_b + (size_t)l * H_;
    const float* gb1 = gate_b1 + (size_t)l * H_;
    const float* gb2 = gate_b2 + (size_t)l * H_;
    const float* fb1 = ff_b1 + (size_t)l * 2 * H_;
    const float* fb2 = ff_b2 + (size_t)l * H_;
    u16* wqg = wt_qg + (size_t)l * 1024 * 256;
    u16* wo = wt_out + (size_t)l * 256 * 256;
    u16* wg2 = wt_g2 + (size_t)l * 256 * 256;
    u16* wf1 = wt_f1 + (size_t)l * 512 * 256;
    u16* wf2 = wt_f2 + (size_t)l * 256 * 512;

    // hb = bf16(LN1(x))
    ln_k<<<M_ / 4, 256, 0, stream>>>(x, ln1_g + l * H_, ln1_b + l * H_, hb);
    // qgb = hb @ [qkv_w | gate_w1] (+biases, silu on g1 cols) -> bf16
    mgemm_k<3, false, false, true><<<dim3(16, 24), 256, 0, stream>>>(
        hb, wqg, qb, nullptr, qgb, 256, 1024, 256, nullptr, gb1);
    // ctx = attention(qgb, biasb[l])  [MFMA]
    attn_mf<<<dim3(12, NH_, B_), 256, 0, stream>>>(
        qgb, biasb + (size_t)l * bias_lstride, ctx, 1024);
    // g2 = g1 @ gate_w2 + gate_b2 (fp32 out); g1 = qgb cols 768..1023
    mgemm_k<0, false, false, false><<<dim3(4, 24), 256, 0, stream>>>(
        (const void*)(qgb + 768), wg2, gb2, nullptr, g2, 256, 256, 1024, nullptr, nullptr);
    // x = x + bf16(ctx * sigmoid(g2)) @ out_w + out_b
    mgemm_k<0, true, true, false><<<dim3(4, 24), 256, 0, stream>>>(
        ctx, wo, ob, x, x, 256, 256, 256, g2, nullptr);
    // hb = bf16(LN2(x))
    ln_k<<<M_ / 4, 256, 0, stream>>>(x, ln2_g + l * H_, ln2_b + l * H_, hb);
    // ffb = bf16(gelu(hb @ ff_w1 + ff_b1))
    mgemm_k<2, false, false, true><<<dim3(8, 24), 256, 0, stream>>>(
        hb, wf1, fb1, nullptr, ffb, 256, 512, 256, nullptr, nullptr);
    // x = x + ffb @ ff_w2 + ff_b2
    mgemm_k<0, true, false, false><<<dim3(4, 24), 256, 0, stream>>>(
        ffb, wf2, fb2, x, x, 512, 256, 512, nullptr, nullptr);
  }

  // pooling head
  ln_k<<<M_ / 4, 256, 0, stream>>>(x, pool_g, pool_beta, hb);
  mgemm_k<1, false, false, false><<<dim3(4, 24), 256, 0, stream>>>(
      hb, wt_p, pool_b, nullptr, ctx, 256, 256, 256, nullptr, nullptr);
  energy_k<<<B_, 256, 0, stream>>>(ctx, mask, eh_w, eh_b, eout);
}